// Round 13
// baseline (438.764 us; speedup 1.0000x reference)
//
#include <hip/hip_runtime.h>
#include <hip/hip_bf16.h>

#define Bb 4
#define Tt 256
#define Uu 128
#define H1 512
#define H2 640
#define Dd 640
#define V1c 1025

typedef __bf16 bf16x8 __attribute__((ext_vector_type(8)));
typedef unsigned short ushort8 __attribute__((ext_vector_type(8)));
typedef unsigned short ushort4v __attribute__((ext_vector_type(4)));
typedef float floatx4 __attribute__((ext_vector_type(4)));

static __device__ __forceinline__ unsigned short f2bf(float x) {
    union { float f; unsigned u; } a; a.f = x;
    unsigned r = a.u + 0x7fffu + ((a.u >> 16) & 1u);
    return (unsigned short)(r >> 16);
}
static __device__ __forceinline__ float bf2f(unsigned short x) {
    union { unsigned u; float f; } a; a.u = ((unsigned)x) << 16; return a.f;
}
static __device__ __forceinline__ void gload_lds16(const void* gsrc, void* ldst) {
    __builtin_amdgcn_global_load_lds(
        (const __attribute__((address_space(1))) void*)gsrc,
        (__attribute__((address_space(3))) void*)ldst, 16, 0, 0);
}

// ---------------- f and g linear layers, fused in one launch ----------------
__global__ __launch_bounds__(640) void fg_fused(const float* __restrict__ enc,
                                                const float* __restrict__ Wenc,
                                                const float* __restrict__ benc,
                                                float* __restrict__ f,
                                                const float* __restrict__ pred,
                                                const float* __restrict__ Wpred,
                                                const float* __restrict__ bpred,
                                                float* __restrict__ g) {
    __shared__ float s[640 * 8];
    const bool isF = blockIdx.x < 128;
    const float* in   = isF ? enc : pred;
    const float* W    = isF ? Wenc : Wpred;
    const float* bias = isF ? benc : bpred;
    float* out        = isF ? f : g;
    const int H    = isF ? H1 : H2;
    const int Tdim = isF ? Tt : Uu;
    const int blk  = isF ? (int)blockIdx.x : (int)blockIdx.x - 128;
    const int tBlocks = Tdim >> 3;
    const int b  = blk / tBlocks;
    const int t0 = (blk % tBlocks) << 3;
    const float* inB = in + (size_t)b * H * Tdim + t0;
    const int tid = threadIdx.x;

    for (int h = tid; h < H; h += 640) {
        float4 v0 = *(const float4*)(inB + (size_t)h * Tdim);
        float4 v1 = *(const float4*)(inB + (size_t)h * Tdim + 4);
        *(float4*)(&s[h * 8])     = v0;
        *(float4*)(&s[h * 8 + 4]) = v1;
    }
    __syncthreads();

    const int d = tid;
    float acc[8];
    #pragma unroll
    for (int j = 0; j < 8; ++j) acc[j] = 0.f;
    #pragma unroll 4
    for (int h = 0; h < H; ++h) {
        float w = W[(size_t)h * Dd + d];
        float4 s0 = *(const float4*)(&s[h * 8]);
        float4 s1 = *(const float4*)(&s[h * 8 + 4]);
        acc[0] += s0.x * w; acc[1] += s0.y * w; acc[2] += s0.z * w; acc[3] += s0.w * w;
        acc[4] += s1.x * w; acc[5] += s1.y * w; acc[6] += s1.z * w; acc[7] += s1.w * w;
    }
    float bv = bias[d];
    float* o = out + ((size_t)b * Tdim + t0) * Dd + d;
    #pragma unroll
    for (int j = 0; j < 8; ++j) o[(size_t)j * Dd] = acc[j] + bv;
}

// ---------------- W_out -> Wb2 swizzled fragment layout + wtail ----------------
// Wb2[w][ksg][nt][l15][lg][8] (ushort): per-(wave,k-step) B-fragment order; each
// B-load instruction reads 1KB contiguous.
__global__ __launch_bounds__(256) void conv_wout2(const float* __restrict__ Wout,
                                                  unsigned short* __restrict__ Wb2,
                                                  float* __restrict__ wtail) {
    __shared__ float tile[32][128];
    const int blk = blockIdx.x;
    const int w = blk / 20;
    const int db = blk % 20;
    const int tid = threadIdx.x;

    #pragma unroll
    for (int i = 0; i < 16; ++i) {
        int idx = tid + 256 * i;
        int d_loc = idx >> 7;
        int v_loc = idx & 127;
        tile[d_loc][v_loc] = Wout[(size_t)(db * 32 + d_loc) * V1c + w * 128 + v_loc];
    }
    __syncthreads();

    #pragma unroll
    for (int k = 0; k < 2; ++k) {
        int gidx = tid * 2 + k;
        int nt  = gidx >> 6;
        int rem = gidx & 63;
        int l15 = rem >> 2;
        int lg  = rem & 3;
        int v_loc = nt * 16 + l15;
        ushort8 pk;
        #pragma unroll
        for (int j = 0; j < 8; ++j) pk[j] = f2bf(tile[lg * 8 + j][v_loc]);
        *(ushort8*)(Wb2 + (size_t)w * 81920 + db * 4096 + gidx * 8) = pk;
    }

    if (blk == 0) {
        for (int dd = tid; dd < Dd; dd += 256) wtail[dd] = Wout[(size_t)dd * V1c + 1024];
    }
}

// ---------------- h materialization: h[b,t,u,:] = bf16(relu(f+g)) ----------------
// grid 1024 = (b,t); 512 thr; plain stores so h (168MB) stays L3-resident.
__global__ __launch_bounds__(512) void h_mat(const float* __restrict__ f,
                                             const float* __restrict__ g,
                                             unsigned short* __restrict__ h) {
    __shared__ float fr[640];
    const int blk = blockIdx.x;
    const int b = blk >> 8;
    const int t = blk & 255;
    const int tid = threadIdx.x;
    if (tid < 160) *(float4*)(&fr[tid * 4]) = *(const float4*)(f + ((size_t)b * Tt + t) * Dd + tid * 4);
    __syncthreads();
    const int u = tid >> 2;      // 0..127
    const int q = tid & 3;
    const float* grow = g + ((size_t)b * Uu + u) * Dd;
    unsigned short* hrow = h + ((size_t)(b * Tt + t) * Uu + u) * (size_t)Dd;
    #pragma unroll 4
    for (int j = 0; j < 20; ++j) {
        int o = j * 4 + q;           // oct 0..79
        int c0 = o * 8;
        float4 ga = *(const float4*)(grow + c0);
        float4 gb = *(const float4*)(grow + c0 + 4);
        float4 fa = *(const float4*)(&fr[c0]);
        float4 fb = *(const float4*)(&fr[c0 + 4]);
        float h0 = fa.x + ga.x; h0 = h0 > 0.f ? h0 : 0.f;
        float h1 = fa.y + ga.y; h1 = h1 > 0.f ? h1 : 0.f;
        float h2 = fa.z + ga.z; h2 = h2 > 0.f ? h2 : 0.f;
        float h3 = fa.w + ga.w; h3 = h3 > 0.f ? h3 : 0.f;
        float h4 = fb.x + gb.x; h4 = h4 > 0.f ? h4 : 0.f;
        float h5 = fb.y + gb.y; h5 = h5 > 0.f ? h5 : 0.f;
        float h6 = fb.z + gb.z; h6 = h6 > 0.f ? h6 : 0.f;
        float h7 = fb.w + gb.w; h7 = h7 > 0.f ? h7 : 0.f;
        ushort8 pk;
        pk[0] = f2bf(h0); pk[1] = f2bf(h1); pk[2] = f2bf(h2); pk[3] = f2bf(h3);
        pk[4] = f2bf(h4); pk[5] = f2bf(h5); pk[6] = f2bf(h6); pk[7] = f2bf(h7);
        *(ushort8*)(hrow + c0) = pk;
    }
}

// ---------------- fused joint + log-softmax ----------------
// 2048 blocks x 512 thr (8 waves). Block: 64 rows x 1025 cols; wave tile 64x128.
// R13 = R12 (Wb2 contiguous B, full-panel, 20-step loop, 4x16-row epilogue)
// + async global_load_lds staging of the precomputed h panel (zero VALU).
// LDS slot trick: slot s -> row s/41, col-slot s%41 => linear dest == 328-stride layout.
__global__ __launch_bounds__(512, 2) void joint_main(const unsigned short* __restrict__ h,
                                                     const unsigned short* __restrict__ Wb2,
                                                     const float* __restrict__ wtail,
                                                     const float* __restrict__ b_out,
                                                     float* __restrict__ out) {
    __shared__ __align__(16) union UU {
        unsigned short hlds[2 * 64 * 328];   // 83,968 B (two half-panels, stride 328)
        float sOut[16 * 1025];               // 65,600 B (aliases dead hlds in epilogue)
    } u;
    __shared__ float wtld[640];
    __shared__ float sPart[8 * 64];
    __shared__ float sRed[64];
    __shared__ float sTail[64];

    const int tid = threadIdx.x;
    const int l = tid & 63;
    const int w = tid >> 6;
    const int l15 = l & 15;
    const int lg = l >> 4;

    const int blk = blockIdx.x;
    const int uhalf = blk & 1;
    const int t = (blk >> 1) & 255;
    const int b = blk >> 9;
    const int u0 = uhalf * 64;
    const size_t rowbase = (size_t)(b * Tt + t) * Uu + u0;
    const unsigned short* hbase = h + rowbase * (size_t)Dd;   // 64 contiguous rows

    // ---- issue async stage of BOTH halves (no VALU, no dest regs) ----
    #pragma unroll
    for (int hh = 0; hh < 2; ++hh) {
        const unsigned short* hsrc = hbase + hh * 320;
        #pragma unroll
        for (int r = 0; r < 6; ++r) {
            int s = tid + 512 * r;
            if (s < 2624) {
                unsigned row = (unsigned)s / 41u;
                unsigned sir = (unsigned)s - row * 41u;
                if (sir > 39u) sir = 39u;
                gload_lds16(hsrc + (size_t)row * Dd + sir * 8, &u.hlds[hh * 20992 + s * 8]);
            }
        }
    }
    // stage wtail (fp32) into LDS
    for (int i = tid; i < Dd; i += 512) wtld[i] = wtail[i];

    floatx4 acc[4][8];
    #pragma unroll
    for (int i = 0; i < 4; ++i)
        #pragma unroll
        for (int j = 0; j < 8; ++j) acc[i][j] = (floatx4){0.f, 0.f, 0.f, 0.f};

    const unsigned short* __restrict__ bbase = Wb2 + (size_t)w * 81920 + (l15 * 32 + lg * 8);
    float tailAcc = 0.f;
    const int srow = w * 8 + (l >> 3);
    const int ssub = l & 7;

    __syncthreads();   // stage + wtld landed

    // ---- K loop: 20 steps of 32, B double-buffered in regs, no barriers ----
    {
        ushort8 Bbuf[2][8];
        #pragma unroll
        for (int nt = 0; nt < 8; ++nt)
            Bbuf[0][nt] = *(const ushort8*)(bbase + nt * 512);
        #pragma unroll
        for (int ksg = 0; ksg < 20; ++ksg) {
            if (ksg < 19) {
                #pragma unroll
                for (int nt = 0; nt < 8; ++nt)
                    Bbuf[(ksg + 1) & 1][nt] =
                        *(const ushort8*)(bbase + (ksg + 1) * 4096 + nt * 512);
            }
            const int bufo = (ksg >= 10) ? 20992 : 0;
            const int ks = (ksg >= 10) ? (ksg - 10) : ksg;
            bf16x8 afrag[4];
            #pragma unroll
            for (int mt = 0; mt < 4; ++mt) {
                ushort8 av = *(const ushort8*)(&u.hlds[bufo + (mt * 16 + l15) * 328 + ks * 32 + lg * 8]);
                afrag[mt] = __builtin_bit_cast(bf16x8, av);
            }
            #pragma unroll
            for (int nt = 0; nt < 8; ++nt) {
                bf16x8 bfrag = __builtin_bit_cast(bf16x8, Bbuf[ksg & 1][nt]);
                #pragma unroll
                for (int mt = 0; mt < 4; ++mt) {
                    acc[mt][nt] = __builtin_amdgcn_mfma_f32_16x16x32_bf16(
                        afrag[mt], bfrag, acc[mt][nt], 0, 0, 0);
                }
            }
        }
    }

    // ---- tail column: dot(h_row, wtail) from LDS ----
    #pragma unroll
    for (int j = 0; j < 20; ++j) {
        int c4 = ssub + 8 * j;                 // 0..159
        int half = (j >= 10) ? 1 : 0;
        int cloc = c4 - half * 80;
        ushort4v hv = *(const ushort4v*)(&u.hlds[half * 20992 + srow * 328 + cloc * 4]);
        float4 wv = *(const float4*)(&wtld[c4 * 4]);
        tailAcc += bf2f(hv.x) * wv.x + bf2f(hv.y) * wv.y +
                   bf2f(hv.z) * wv.z + bf2f(hv.w) * wv.w;
    }

    tailAcc += __shfl_xor(tailAcc, 1);
    tailAcc += __shfl_xor(tailAcc, 2);
    tailAcc += __shfl_xor(tailAcc, 4);
    if (ssub == 0) sTail[srow] = tailAcc + b_out[1024];

    // ---- + b_out ----
    #pragma unroll
    for (int nt = 0; nt < 8; ++nt) {
        float bo = b_out[w * 128 + nt * 16 + l15];
        #pragma unroll
        for (int mt = 0; mt < 4; ++mt)
            #pragma unroll
            for (int r = 0; r < 4; ++r) acc[mt][nt][r] += bo;
    }

    // ---- row max ----
    #pragma unroll
    for (int mt = 0; mt < 4; ++mt) {
        #pragma unroll
        for (int r = 0; r < 4; ++r) {
            float m = acc[mt][0][r];
            #pragma unroll
            for (int nt = 1; nt < 8; ++nt) m = fmaxf(m, acc[mt][nt][r]);
            #pragma unroll
            for (int msk = 1; msk < 16; msk <<= 1) m = fmaxf(m, __shfl_xor(m, msk));
            if (l15 == 0) sPart[w * 64 + mt * 16 + lg * 4 + r] = m;
        }
    }
    __syncthreads();
    if (tid < 64) {
        float m = sTail[tid];
        #pragma unroll
        for (int ww = 0; ww < 8; ++ww) m = fmaxf(m, sPart[ww * 64 + tid]);
        sRed[tid] = m;
    }
    __syncthreads();

    // ---- sum exp ----
    #pragma unroll
    for (int mt = 0; mt < 4; ++mt) {
        #pragma unroll
        for (int r = 0; r < 4; ++r) {
            int row = mt * 16 + lg * 4 + r;
            float mx = sRed[row];
            float sv = 0.f;
            #pragma unroll
            for (int nt = 0; nt < 8; ++nt) sv += __expf(acc[mt][nt][r] - mx);
            #pragma unroll
            for (int msk = 1; msk < 16; msk <<= 1) sv += __shfl_xor(sv, msk);
            if (l15 == 0) sPart[w * 64 + row] = sv;
        }
    }
    __syncthreads();
    if (tid < 64) {
        float mx = sRed[tid];
        float sv = __expf(sTail[tid] - mx);
        #pragma unroll
        for (int ww = 0; ww < 8; ++ww) sv += sPart[ww * 64 + tid];
        sRed[tid] = mx + logf(sv);  // lse
    }
    __syncthreads();   // sRed ready; hlds dead -> sOut aliasing OK

    // ---- write: 4 groups of 16 rows (group g = acc[mt=g]), LDS-staged drain ----
    #pragma unroll
    for (int grp = 0; grp < 4; ++grp) {
        #pragma unroll
        for (int nt = 0; nt < 8; ++nt) {
            #pragma unroll
            for (int r = 0; r < 4; ++r) {
                u.sOut[(lg * 4 + r) * 1025 + w * 128 + nt * 16 + l15] =
                    acc[grp][nt][r] - sRed[grp * 16 + lg * 4 + r];
            }
        }
        if (tid < 16) u.sOut[tid * 1025 + 1024] = sTail[grp * 16 + tid] - sRed[grp * 16 + tid];
        __syncthreads();
        // 16*1025 = 16400 floats = 4100 float4
        float* outp = out + (rowbase + grp * 16) * (size_t)V1c;
        #pragma unroll
        for (int k = 0; k < 8; ++k) {
            int i4 = tid + 512 * k;
            floatx4 v = *(const floatx4*)(&u.sOut[4 * i4]);
            __builtin_nontemporal_store(v, (floatx4*)(outp + 4 * i4));
        }
        if (tid < 4) {
            int i4 = tid + 4096;
            floatx4 v = *(const floatx4*)(&u.sOut[4 * i4]);
            __builtin_nontemporal_store(v, (floatx4*)(outp + 4 * i4));
        }
        __syncthreads();
    }
}

extern "C" void kernel_launch(void* const* d_in, const int* in_sizes, int n_in,
                              void* d_out, int out_size, void* d_ws, size_t ws_size,
                              hipStream_t stream) {
    const float* enc   = (const float*)d_in[0];
    const float* pred  = (const float*)d_in[1];
    const float* Wenc  = (const float*)d_in[2];
    const float* benc  = (const float*)d_in[3];
    const float* Wpred = (const float*)d_in[4];
    const float* bpred = (const float*)d_in[5];
    const float* Wout  = (const float*)d_in[6];
    const float* bout  = (const float*)d_in[7];

    float* f = (float*)d_ws;                                     // 2.62 MB
    float* g = f + (size_t)Bb * Tt * Dd;                         // 1.31 MB
    unsigned short* Wb2 = (unsigned short*)(g + (size_t)Bb * Uu * Dd);  // 1.31 MB
    float* wtail = (float*)(Wb2 + 8 * 81920);                    // 2.5 KB
    unsigned short* h = (unsigned short*)((char*)d_ws + 6ull * 1024 * 1024);  // 168 MB

    fg_fused<<<192, 640, 0, stream>>>(enc, Wenc, benc, f, pred, Wpred, bpred, g);
    conv_wout2<<<160, 256, 0, stream>>>(Wout, Wb2, wtail);
    h_mat<<<Bb * Tt, 512, 0, stream>>>(f, g, h);
    joint_main<<<Bb * Tt * 2, 512, 0, stream>>>(h, Wb2, wtail, bout, (float*)d_out);
}

// Round 14
// 404.515 us; speedup vs baseline: 1.0847x; 1.0847x over previous
//
#include <hip/hip_runtime.h>
#include <hip/hip_bf16.h>

#define Bb 4
#define Tt 256
#define Uu 128
#define H1 512
#define H2 640
#define Dd 640
#define V1c 1025

typedef __bf16 bf16x8 __attribute__((ext_vector_type(8)));
typedef unsigned short ushort8 __attribute__((ext_vector_type(8)));
typedef unsigned short ushort4v __attribute__((ext_vector_type(4)));
typedef float floatx4 __attribute__((ext_vector_type(4)));

static __device__ __forceinline__ unsigned short f2bf(float x) {
    union { float f; unsigned u; } a; a.f = x;
    unsigned r = a.u + 0x7fffu + ((a.u >> 16) & 1u);
    return (unsigned short)(r >> 16);
}
// HW packed f32->bf16 RTNE: dst.lo = bf16(lo), dst.hi = bf16(hi)
static __device__ __forceinline__ unsigned cvt_pk_bf16(float lo, float hi) {
    unsigned r;
    asm("v_cvt_pk_bf16_f32 %0, %1, %2" : "=v"(r) : "v"(lo), "v"(hi));
    return r;
}

// ---------------- prep: fg linears (blocks 0..191) + Wb2 swizzle (192..351) ----------------
__global__ __launch_bounds__(640) void prep(const float* __restrict__ enc,
                                            const float* __restrict__ Wenc,
                                            const float* __restrict__ benc,
                                            float* __restrict__ f,
                                            const float* __restrict__ pred,
                                            const float* __restrict__ Wpred,
                                            const float* __restrict__ bpred,
                                            float* __restrict__ g,
                                            const float* __restrict__ Wout,
                                            unsigned short* __restrict__ Wb2,
                                            float* __restrict__ wtail) {
    __shared__ __align__(16) float sh[640 * 8];
    const int tid = threadIdx.x;

    if (blockIdx.x < 192) {
        // ---- f / g linear ----
        const bool isF = blockIdx.x < 128;
        const float* in   = isF ? enc : pred;
        const float* W    = isF ? Wenc : Wpred;
        const float* bias = isF ? benc : bpred;
        float* out        = isF ? f : g;
        const int H    = isF ? H1 : H2;
        const int Tdim = isF ? Tt : Uu;
        const int blk  = isF ? (int)blockIdx.x : (int)blockIdx.x - 128;
        const int tBlocks = Tdim >> 3;
        const int b  = blk / tBlocks;
        const int t0 = (blk % tBlocks) << 3;
        const float* inB = in + (size_t)b * H * Tdim + t0;

        for (int h = tid; h < H; h += 640) {
            float4 v0 = *(const float4*)(inB + (size_t)h * Tdim);
            float4 v1 = *(const float4*)(inB + (size_t)h * Tdim + 4);
            *(float4*)(&sh[h * 8])     = v0;
            *(float4*)(&sh[h * 8 + 4]) = v1;
        }
        __syncthreads();

        const int d = tid;
        float acc[8];
        #pragma unroll
        for (int j = 0; j < 8; ++j) acc[j] = 0.f;
        #pragma unroll 4
        for (int h = 0; h < H; ++h) {
            float w = W[(size_t)h * Dd + d];
            float4 s0 = *(const float4*)(&sh[h * 8]);
            float4 s1 = *(const float4*)(&sh[h * 8 + 4]);
            acc[0] += s0.x * w; acc[1] += s0.y * w; acc[2] += s0.z * w; acc[3] += s0.w * w;
            acc[4] += s1.x * w; acc[5] += s1.y * w; acc[6] += s1.z * w; acc[7] += s1.w * w;
        }
        float bv = bias[d];
        float* o = out + ((size_t)b * Tdim + t0) * Dd + d;
        #pragma unroll
        for (int j = 0; j < 8; ++j) o[(size_t)j * Dd] = acc[j] + bv;
    } else {
        // ---- W_out -> Wb2[w][ksg][nt][l15][lg][8] fragment layout ----
        float (*tile)[129] = (float(*)[129])sh;    // 32 x 129 (padded)
        const int blk2 = blockIdx.x - 192;         // 0..159
        const int w = blk2 / 20;
        const int db = blk2 % 20;

        for (int idx = tid; idx < 4096; idx += 640) {
            int d_loc = idx >> 7;
            int v_loc = idx & 127;
            tile[d_loc][v_loc] = Wout[(size_t)(db * 32 + d_loc) * V1c + w * 128 + v_loc];
        }
        __syncthreads();

        if (tid < 512) {
            int gidx = tid;
            int nt  = gidx >> 6;
            int rem = gidx & 63;
            int l15 = rem >> 2;
            int lg  = rem & 3;
            int v_loc = nt * 16 + l15;
            ushort8 pk;
            #pragma unroll
            for (int j = 0; j < 8; ++j) pk[j] = f2bf(tile[lg * 8 + j][v_loc]);
            *(ushort8*)(Wb2 + (size_t)w * 81920 + db * 4096 + gidx * 8) = pk;
        }
        if (blk2 == 0 && tid < Dd) wtail[tid] = Wout[(size_t)tid * V1c + 1024];
    }
}

// ---------------- fused joint + log-softmax ----------------
// 2048 blocks x 512 thr (8 waves). Block: 64 rows x 1025 cols; wave tile 64x128.
// R14 = R12 + (a) cvt_pk_bf16 HW pack in staging, (b) tail-column dot folded
// into staging (fp32 h, wtail from L1-hot global), (c) ping-pong 8-row epilogue.
__global__ __launch_bounds__(512, 2) void joint_main(const float* __restrict__ f,
                                                     const float* __restrict__ g,
                                                     const unsigned short* __restrict__ Wb2,
                                                     const float* __restrict__ wtail,
                                                     const float* __restrict__ b_out,
                                                     float* __restrict__ out) {
    __shared__ __align__(16) union UU {
        unsigned short hlds[2 * 64 * 328];   // 83,968 B (two half-panels, stride 328)
        float sOut[2 * 8 * 1025];            // 65,600 B ping-pong (aliases dead hlds)
    } u;
    __shared__ float sPart[8 * 64];
    __shared__ float sRed[64];
    __shared__ float sTail[64];

    const int tid = threadIdx.x;
    const int l = tid & 63;
    const int w = tid >> 6;
    const int l15 = l & 15;
    const int lg = l >> 4;

    const int blk = blockIdx.x;
    const int uhalf = blk & 1;
    const int t = (blk >> 1) & 255;
    const int b = blk >> 9;
    const int u0 = uhalf * 64;
    const size_t fbase = ((size_t)b * Tt + t) * Dd;
    const size_t gbase = ((size_t)b * Uu + u0) * Dd;
    const size_t rowbase = (size_t)(b * Tt + t) * Uu + u0;

    floatx4 acc[4][8];
    #pragma unroll
    for (int i = 0; i < 4; ++i)
        #pragma unroll
        for (int j = 0; j < 8; ++j) acc[i][j] = (floatx4){0.f, 0.f, 0.f, 0.f};

    const unsigned short* __restrict__ bbase = Wb2 + (size_t)w * 81920 + (l15 * 32 + lg * 8);
    float tailAcc = 0.f;
    const int srow = w * 8 + (l >> 3);
    const int ssub = l & 7;

    // ---- stage FULL h = relu(f+g) panel (64 x 640 bf16) + fold tail-col dot ----
    {
        const int row = tid >> 3;
        const float* frow = f + fbase;
        const float* grow = g + gbase + (size_t)row * Dd;
        #pragma unroll
        for (int j = 0; j < 20; ++j) {
            int c4 = (tid & 7) + 8 * j;        // float4 slot 0..159
            int d = c4 * 4;
            int half = (j >= 10) ? 1 : 0;
            int cloc = c4 - half * 80;
            float4 fv = *(const float4*)(frow + d);
            float4 gv = *(const float4*)(grow + d);
            float4 wv = *(const float4*)(wtail + d);
            float h0 = fmaxf(fv.x + gv.x, 0.f);
            float h1 = fmaxf(fv.y + gv.y, 0.f);
            float h2 = fmaxf(fv.z + gv.z, 0.f);
            float h3 = fmaxf(fv.w + gv.w, 0.f);
            tailAcc += h0 * wv.x + h1 * wv.y + h2 * wv.z + h3 * wv.w;
            uint2 pk;
            pk.x = cvt_pk_bf16(h0, h1);
            pk.y = cvt_pk_bf16(h2, h3);
            *(uint2*)(&u.hlds[half * 20992 + row * 328 + cloc * 4]) = pk;
        }
    }
    __syncthreads();

    // ---- K loop: 20 steps of 32, B double-buffered in regs, no barriers ----
    {
        ushort8 Bbuf[2][8];
        #pragma unroll
        for (int nt = 0; nt < 8; ++nt)
            Bbuf[0][nt] = *(const ushort8*)(bbase + nt * 512);
        #pragma unroll
        for (int ksg = 0; ksg < 20; ++ksg) {
            if (ksg < 19) {
                #pragma unroll
                for (int nt = 0; nt < 8; ++nt)
                    Bbuf[(ksg + 1) & 1][nt] =
                        *(const ushort8*)(bbase + (ksg + 1) * 4096 + nt * 512);
            }
            const int bufo = (ksg >= 10) ? 20992 : 0;
            const int ks = (ksg >= 10) ? (ksg - 10) : ksg;
            bf16x8 afrag[4];
            #pragma unroll
            for (int mt = 0; mt < 4; ++mt) {
                ushort8 av = *(const ushort8*)(&u.hlds[bufo + (mt * 16 + l15) * 328 + ks * 32 + lg * 8]);
                afrag[mt] = __builtin_bit_cast(bf16x8, av);
            }
            #pragma unroll
            for (int nt = 0; nt < 8; ++nt) {
                bf16x8 bfrag = __builtin_bit_cast(bf16x8, Bbuf[ksg & 1][nt]);
                #pragma unroll
                for (int mt = 0; mt < 4; ++mt) {
                    acc[mt][nt] = __builtin_amdgcn_mfma_f32_16x16x32_bf16(
                        afrag[mt], bfrag, acc[mt][nt], 0, 0, 0);
                }
            }
        }
    }

    // ---- tail column reduce (partials computed during staging) ----
    tailAcc += __shfl_xor(tailAcc, 1);
    tailAcc += __shfl_xor(tailAcc, 2);
    tailAcc += __shfl_xor(tailAcc, 4);
    if (ssub == 0) sTail[srow] = tailAcc + b_out[1024];

    // ---- + b_out ----
    #pragma unroll
    for (int nt = 0; nt < 8; ++nt) {
        float bo = b_out[w * 128 + nt * 16 + l15];
        #pragma unroll
        for (int mt = 0; mt < 4; ++mt)
            #pragma unroll
            for (int r = 0; r < 4; ++r) acc[mt][nt][r] += bo;
    }

    // ---- row max ----
    #pragma unroll
    for (int mt = 0; mt < 4; ++mt) {
        #pragma unroll
        for (int r = 0; r < 4; ++r) {
            float m = acc[mt][0][r];
            #pragma unroll
            for (int nt = 1; nt < 8; ++nt) m = fmaxf(m, acc[mt][nt][r]);
            #pragma unroll
            for (int msk = 1; msk < 16; msk <<= 1) m = fmaxf(m, __shfl_xor(m, msk));
            if (l15 == 0) sPart[w * 64 + mt * 16 + lg * 4 + r] = m;
        }
    }
    __syncthreads();
    if (tid < 64) {
        float m = sTail[tid];
        #pragma unroll
        for (int ww = 0; ww < 8; ++ww) m = fmaxf(m, sPart[ww * 64 + tid]);
        sRed[tid] = m;
    }
    __syncthreads();

    // ---- sum exp ----
    #pragma unroll
    for (int mt = 0; mt < 4; ++mt) {
        #pragma unroll
        for (int r = 0; r < 4; ++r) {
            int row = mt * 16 + lg * 4 + r;
            float mx = sRed[row];
            float sv = 0.f;
            #pragma unroll
            for (int nt = 0; nt < 8; ++nt) sv += __expf(acc[mt][nt][r] - mx);
            #pragma unroll
            for (int msk = 1; msk < 16; msk <<= 1) sv += __shfl_xor(sv, msk);
            if (l15 == 0) sPart[w * 64 + row] = sv;
        }
    }
    __syncthreads();
    if (tid < 64) {
        float mx = sRed[tid];
        float sv = __expf(sTail[tid] - mx);
        #pragma unroll
        for (int ww = 0; ww < 8; ++ww) sv += sPart[ww * 64 + tid];
        sRed[tid] = mx + logf(sv);  // lse
    }
    __syncthreads();   // sRed ready; hlds dead -> sOut ping-pong aliasing OK

    // ---- write: 8 groups of 8 rows, ping-pong LDS buffers; drain(g-1) overlaps fill(g) ----
    {
        // fill(grp) into buf[grp&1]
        #define FILL(grp_)                                                            \
        {                                                                             \
            const int mt_ = (grp_) >> 1;                                              \
            const int half8_ = (grp_) & 1;                                            \
            float* buf_ = u.sOut + ((grp_) & 1) * 8200;                               \
            if ((lg >> 1) == half8_) {                                                \
                const int rl_ = (lg & 1) * 4;                                         \
                _Pragma("unroll")                                                     \
                for (int nt = 0; nt < 8; ++nt) {                                      \
                    _Pragma("unroll")                                                 \
                    for (int r = 0; r < 4; ++r) {                                     \
                        buf_[(rl_ + r) * 1025 + w * 128 + nt * 16 + l15] =            \
                            acc[mt_][nt][r] - sRed[(grp_) * 8 + rl_ + r];             \
                    }                                                                 \
                }                                                                     \
            }                                                                         \
            if (tid < 8) buf_[tid * 1025 + 1024] =                                    \
                sTail[(grp_) * 8 + tid] - sRed[(grp_) * 8 + tid];                     \
        }
        #define DRAIN(grp_)                                                           \
        {                                                                             \
            const float* buf_ = u.sOut + ((grp_) & 1) * 8200;                         \
            float* outp_ = out + (rowbase + (grp_) * 8) * (size_t)V1c;                \
            _Pragma("unroll")                                                         \
            for (int k = 0; k < 4; ++k) {                                             \
                int i4 = tid + 512 * k;                                               \
                floatx4 v = *(const floatx4*)(&buf_[4 * i4]);                         \
                __builtin_nontemporal_store(v, (floatx4*)(outp_ + 4 * i4));           \
            }                                                                         \
            if (tid < 2) {                                                            \
                int i4 = tid + 2048;                                                  \
                floatx4 v = *(const floatx4*)(&buf_[4 * i4]);                         \
                __builtin_nontemporal_store(v, (floatx4*)(outp_ + 4 * i4));           \
            }                                                                         \
        }
        FILL(0);
        __syncthreads();
        #pragma unroll
        for (int gg = 1; gg < 8; ++gg) {
            FILL(gg);
            DRAIN(gg - 1);
            __syncthreads();
        }
        DRAIN(7);
        #undef FILL
        #undef DRAIN
    }
}

extern "C" void kernel_launch(void* const* d_in, const int* in_sizes, int n_in,
                              void* d_out, int out_size, void* d_ws, size_t ws_size,
                              hipStream_t stream) {
    const float* enc   = (const float*)d_in[0];
    const float* pred  = (const float*)d_in[1];
    const float* Wenc  = (const float*)d_in[2];
    const float* benc  = (const float*)d_in[3];
    const float* Wpred = (const float*)d_in[4];
    const float* bpred = (const float*)d_in[5];
    const float* Wout  = (const float*)d_in[6];
    const float* bout  = (const float*)d_in[7];

    float* f = (float*)d_ws;                                     // 655360 f32
    float* g = f + (size_t)Bb * Tt * Dd;                         // 327680 f32
    unsigned short* Wb2 = (unsigned short*)(g + (size_t)Bb * Uu * Dd);  // 655360 u16
    float* wtail = (float*)(Wb2 + 8 * 81920);                    // 640 f32

    prep<<<352, 640, 0, stream>>>(enc, Wenc, benc, f, pred, Wpred, bpred, g,
                                  Wout, Wb2, wtail);
    joint_main<<<Bb * Tt * 2, 512, 0, stream>>>(f, g, Wb2, wtail, bout, (float*)d_out);
}